// Round 1
// 2434.036 us; speedup vs baseline: 1.0193x; 1.0193x over previous
//
#include <hip/hip_runtime.h>

// ---------------------------------------------------------------------------
// attn_mh: q/k/v proj (bf16 MFMA) -> masked softmax attention -> out proj
//          + residual -> LayerNorm.   B=128 S=512 H=1000 NH=8 DK=125
//
// ws element (u16) offsets:
//   XQ=0         Xq bf16 [65536][1024]   (aliased later by Z2)
//   XK=67108864  Xk bf16 [65536][1024]   (aliased later by Y fp32)
//   XV=134217728 Xv bf16 [65536][1024]   (aliased later by Y fp32)
//   WQ/WK/WV/WO at 201326592 + i*1048576  bf16 [1024][1024]
//   QH=205520896 qh bf16 [1024 bnh][512 s][128 dk]  (scaled by 1/sqrt(125))
//   KH=272629760 kh bf16 [1024 bnh][512 s][128 dk]  (dk pad zeroed)
//   VT=339738624 vh bf16 TRANSPOSED [1024 bnh][128 dk][512 s]
//   Z2 = 0 (aliases XQ)  z bf16 [65536][1024]
//   Y  = byte 134217728 (aliases XK/XV)  fp32 [65536][1000]  (z@Wo^T+b+q)
// total ws needed: 813,694,976 bytes
// ---------------------------------------------------------------------------

typedef unsigned short u16;
typedef short short8 __attribute__((ext_vector_type(8)));
typedef float f32x4 __attribute__((ext_vector_type(4)));

#define XQ_E 0ull
#define XK_E 67108864ull
#define XV_E 134217728ull
#define WQ_E 201326592ull
#define WK_E 202375168ull
#define WV_E 203423744ull
#define WO_E 204472320ull
#define QH_E 205520896ull
#define KH_E 272629760ull
#define VT_E 339738624ull
#define Z2_E 0ull
#define Y_BYTE 134217728ull

__device__ __forceinline__ u16 f2bf(float f) {
  unsigned u = __float_as_uint(f);
  u += 0x7fffu + ((u >> 16) & 1u);
  return (u16)(u >> 16);
}

__device__ __forceinline__ void gl_lds16(const void* g, void* l) {
  __builtin_amdgcn_global_load_lds((const __attribute__((address_space(1))) void*)g,
                                   (__attribute__((address_space(3))) void*)l,
                                   16, 0, 0);
}

// ---------------- fp32 -> bf16 convert + K-pad to 1024 ----------------------
__global__ __launch_bounds__(128) void cvt_kernel(
    const float* __restrict__ q, const float* __restrict__ k, const float* __restrict__ v,
    const float* __restrict__ wq, const float* __restrict__ wk,
    const float* __restrict__ wv, const float* __restrict__ wo,
    u16* __restrict__ ws16) {
  const int row = blockIdx.x;
  const int c0 = threadIdx.x * 8;
  const float* src;
  u16* dst;
  bool valid;
  if (row < 196608) {                      // q,k,v rows
    const int m = row >> 16, r = row & 65535;
    src = (m == 0 ? q : (m == 1 ? k : v)) + (size_t)r * 1000;
    dst = ws16 + (size_t)m * 67108864ull + (size_t)r * 1024;
    valid = (c0 < 1000);
  } else {                                 // 4 weight matrices, rows padded to 1024
    const int t2 = row - 196608;
    const int wm = t2 >> 10, r = t2 & 1023;
    const float* W = (wm == 0 ? wq : (wm == 1 ? wk : (wm == 2 ? wv : wo)));
    src = W + (size_t)r * 1000;
    dst = ws16 + WQ_E + (size_t)wm * 1048576ull + (size_t)r * 1024;
    valid = (c0 < 1000) && (r < 1000);
  }
  short8 o = {0, 0, 0, 0, 0, 0, 0, 0};
  if (valid) {
    float4 a = *(const float4*)(src + c0);
    float4 b = *(const float4*)(src + c0 + 4);
    o[0] = (short)f2bf(a.x); o[1] = (short)f2bf(a.y);
    o[2] = (short)f2bf(a.z); o[3] = (short)f2bf(a.w);
    o[4] = (short)f2bf(b.x); o[5] = (short)f2bf(b.y);
    o[6] = (short)f2bf(b.z); o[7] = (short)f2bf(b.w);
  }
  *(short8*)(dst + c0) = o;
}

// zero kh's dk pad (125..127) so score-GEMM K-pad contributes 0
__global__ __launch_bounds__(256) void zpad_kernel(u16* __restrict__ ws16) {
  const int r = blockIdx.x * 256 + threadIdx.x;  // 0..524287 = bnh*512+s
  u16* p = ws16 + KH_E + (size_t)r * 128 + 125;
  p[0] = 0; p[1] = 0; p[2] = 0;
}

// ---------------- NT GEMM, 256x256 tile, BK=64, 8-phase counted-vmcnt -------
// mode 0/1/2: X[q|k|v] @ W^T + b  -> qh(scaled)/kh/vh^T head-major layouts
// mode 3:     Z2 @ Wo^T + b + q   -> Y fp32
//
// Schedule (per K-step = 4 phases; 512 thr; sweep = one 64-row quarter = 8KB):
//   issue order:  p0:{B0,B1(t+1)} p1:{B2,B3} p2:{A0,A2} p3:{A1,A3}
//   consume:      p0 reads all B(t) + A rows 0-31 of wave-half; p1 rows 32-63;
//                 p2/p3 rows 64-127  -> quarter q{2wr} read by p1, q{2wr+1} by p3
//   waits:        end-p1 vmcnt(4)  (drains A1,A3 of t; leaves 4 B(t+1) in flight)
//                 end-p3 vmcnt(2)  (drains B(t+1)+A0,A2(t+1); leaves A1,A3(t+1))
//   -> never vmcnt(0) in steady state; every LDS write lands after the previous
//      tenant's last reader passed a barrier (A(t+1) staged p2/p3, A(t-1) done
//      at p3 of t-1; B(t+1) staged p0/p1, B(t-1) done at p0 of t-1).
// LDS XOR swizzle: 16B slot ^= (row&7)<<4 applied on BOTH the pre-swizzled
// global source (so linear global_load_lds dest stores swizzled data) and the
// ds_read address -> 16-way bank conflict becomes free 2-way.
__global__ __launch_bounds__(512, 2) void gemm_bt(
    u16* __restrict__ ws16,
    const float* __restrict__ bq, const float* __restrict__ bk,
    const float* __restrict__ bv, const float* __restrict__ bo,
    const float* __restrict__ qres, int mode_base) {
  const int mode = mode_base + blockIdx.z;
  const u16* A; const u16* Bw; const float* bias;
  if (mode == 0)      { A = ws16 + XQ_E; Bw = ws16 + WQ_E; bias = bq; }
  else if (mode == 1) { A = ws16 + XK_E; Bw = ws16 + WK_E; bias = bk; }
  else if (mode == 2) { A = ws16 + XV_E; Bw = ws16 + WV_E; bias = bv; }
  else                { A = ws16 + Z2_E; Bw = ws16 + WO_E; bias = bo; }

  __shared__ __attribute__((aligned(16))) u16 lA[2][256 * 64];
  __shared__ __attribute__((aligned(16))) u16 lB[2][256 * 64];

  const int tid = threadIdx.x;
  const int wid = tid >> 6, lane = tid & 63;
  const int wr = wid >> 2, wc = wid & 3;          // 2x4 wave grid, 128x64 per wave
  const int fr = lane & 15, quad = lane >> 4;
  const int widl = wid * 512;                     // wave's 1KB slice inside a quarter

  // XCD-contiguous, n-fastest block swizzle (gridDim.x == 1024 == 8*128)
  const int f = blockIdx.x;
  const int logical = (f & 7) * 128 + (f >> 3);
  const int mt = logical >> 2, nt = logical & 3;
  const int m0 = mt * 256, n0 = nt * 256;

  // staging geometry: thread covers row r8 = tid>>3, 16B slot (tid&7) of 128B row
  const int r8 = tid >> 3;
  const int swz_cb = ((tid & 7) * 16) ^ ((r8 & 7) << 4);   // inverse-swizzled source col
  const char* srcA = (const char*)(A + (size_t)m0 * 1024) + (size_t)r8 * 2048 + swz_cb;
  const char* srcB = (const char*)(Bw + (size_t)n0 * 1024) + (size_t)r8 * 2048 + swz_cb;

  auto stA = [&](int b2, int q, int kb) {
    gl_lds16(srcA + (size_t)q * 131072 + kb, (void*)(&lA[b2][q * 4096 + widl]));
  };
  auto stB = [&](int b2, int q, int kb) {
    gl_lds16(srcB + (size_t)q * 131072 + kb, (void*)(&lB[b2][q * 4096 + widl]));
  };

  const f32x4 zz = {0.f, 0.f, 0.f, 0.f};
  f32x4 acc[8][4];
#pragma unroll
  for (int mi = 0; mi < 8; ++mi)
#pragma unroll
    for (int ni = 0; ni < 4; ++ni) acc[mi][ni] = zz;

  // prologue: K-step 0, issue order {B0 B1 B2 B3 A0 A2} then {A1 A3}
  stB(0, 0, 0); stB(0, 1, 0); stB(0, 2, 0); stB(0, 3, 0);
  stA(0, 0, 0); stA(0, 2, 0); stA(0, 1, 0); stA(0, 3, 0);
  asm volatile("s_waitcnt vmcnt(2)" ::: "memory");
  asm volatile("s_barrier" ::: "memory");

  const int rowA = (wr * 128 + fr) * 128;   // byte base of lane's A frag rows (+mi*2048)
  const int rowB = (wc * 64 + fr) * 128;
  const int swr = (fr & 7) << 4;

  short8 bfr[4][2];

#pragma unroll 2
  for (int t = 0; t < 16; ++t) {
    const int buf = t & 1, nb = buf ^ 1;
    const char* tA = (const char*)(&lA[buf][0]);
    const char* tB = (const char*)(&lB[buf][0]);
    const int kb = (t + 1) * 128;
    const bool pf = (t < 15);

#pragma unroll
    for (int p = 0; p < 4; ++p) {
      short8 afr[2][2];
#pragma unroll
      for (int j = 0; j < 2; ++j)
#pragma unroll
        for (int ks = 0; ks < 2; ++ks)
          afr[j][ks] = *(const short8*)(tA + rowA + (p * 2 + j) * 2048 +
                                        ((ks * 64 + quad * 16) ^ swr));
      if (p == 0) {
#pragma unroll
        for (int ni = 0; ni < 4; ++ni)
#pragma unroll
          for (int ks = 0; ks < 2; ++ks)
            bfr[ni][ks] = *(const short8*)(tB + rowB + ni * 2048 +
                                           ((ks * 64 + quad * 16) ^ swr));
      }
      if (pf) {
        if (p == 0)      { stB(nb, 0, kb); stB(nb, 1, kb); }
        else if (p == 1) { stB(nb, 2, kb); stB(nb, 3, kb); }
        else if (p == 2) { stA(nb, 0, kb); stA(nb, 2, kb); }
        else             { stA(nb, 1, kb); stA(nb, 3, kb); }
      }
      asm volatile("s_barrier" ::: "memory");
      asm volatile("s_waitcnt lgkmcnt(0)" ::: "memory");
      __builtin_amdgcn_s_setprio(1);
#pragma unroll
      for (int j = 0; j < 2; ++j)
#pragma unroll
        for (int ks = 0; ks < 2; ++ks)
#pragma unroll
          for (int ni = 0; ni < 4; ++ni)
            acc[p * 2 + j][ni] = __builtin_amdgcn_mfma_f32_16x16x32_bf16(
                afr[j][ks], bfr[ni][ks], acc[p * 2 + j][ni], 0, 0, 0);
      __builtin_amdgcn_s_setprio(0);
      if (p == 1) {
        if (pf) asm volatile("s_waitcnt vmcnt(4)" ::: "memory");
        else    asm volatile("s_waitcnt vmcnt(0)" ::: "memory");
      } else if (p == 3 && pf) {
        asm volatile("s_waitcnt vmcnt(2)" ::: "memory");
      }
      asm volatile("s_barrier" ::: "memory");
    }
  }

  // epilogue: C/D layout col=lane&15, row=quad*4+r (m89/m91 verified)
#pragma unroll
  for (int mi = 0; mi < 8; ++mi)
#pragma unroll
    for (int ni = 0; ni < 4; ++ni)
#pragma unroll
      for (int r = 0; r < 4; ++r) {
        const int gr = m0 + wr * 128 + mi * 16 + quad * 4 + r;
        const int gc = n0 + wc * 64 + ni * 16 + fr;
        if (gc >= 1000) continue;
        float val = acc[mi][ni][r] + bias[gc];
        if (mode <= 1) {
          if (mode == 0) val *= 0.08944271909999159f;   // 1/sqrt(125) folded into qh
          const int head = gc / 125, dk = gc - head * 125;
          const int b = gr >> 9, s = gr & 511;
          u16* dst = ws16 + (mode == 0 ? QH_E : KH_E);
          dst[((size_t)((b * 8 + head) * 512 + s)) * 128 + dk] = f2bf(val);
        } else if (mode == 2) {
          const int head = gc / 125, dk = gc - head * 125;
          const int b = gr >> 9, s = gr & 511;
          ws16[VT_E + ((size_t)((b * 8 + head) * 128 + dk)) * 512 + s] = f2bf(val);
        } else {
          float* Y = (float*)((char*)ws16 + Y_BYTE);
          Y[(size_t)gr * 1000 + gc] = val + qres[(size_t)gr * 1000 + gc];
        }
      }
}

// ---------------- attention: 1 block = (bnh, 64 q rows), 4 waves ------------
__global__ __launch_bounds__(256, 2) void attn_kernel(
    u16* __restrict__ ws16, const int* __restrict__ maskp) {
  const u16* QH = ws16 + QH_E;
  const u16* KH = ws16 + KH_E;
  const u16* VT = ws16 + VT_E;
  u16* Z2 = ws16 + Z2_E;

  const int qt = blockIdx.x, bnh = blockIdx.y;
  const int b = bnh >> 3, head = bnh & 7;
  const int tid = threadIdx.x, w = tid >> 6, lane = tid & 63;
  const int fr = lane & 15, quad = lane >> 4, fq = quad * 8;

  __shared__ __attribute__((aligned(16))) u16 lQ[64 * 128];
  __shared__ __attribute__((aligned(16))) u16 lKV[64 * 128];
  __shared__ __attribute__((aligned(16))) u16 lP[4][16 * 72];  // pitch 72: 16B-aligned rows
  __shared__ float lM[512];

  {  // mask -> LDS (True means "set score to -10000")
    const int* mp = maskp + b * 512;
    lM[tid] = mp[tid] ? 1.0f : 0.0f;
    lM[tid + 256] = mp[tid + 256] ? 1.0f : 0.0f;
  }
  {  // stage qh tile [64 q][128 dk]
    const int lrow = lane >> 4, lc = (lane & 15) * 8;
#pragma unroll
    for (int i = 0; i < 4; ++i) {
      const int rbase = w * 16 + i * 4;
      gl_lds16(QH + ((size_t)(bnh * 512 + qt * 64 + rbase + lrow)) * 128 + lc,
               (void*)(lQ + rbase * 128));
    }
  }
  __syncthreads();

  short8 af[4];  // wave's 16 q-rows, all 4 k-slices of dk (lQ is stable)
#pragma unroll
  for (int ks = 0; ks < 4; ++ks)
    af[ks] = *(const short8*)(lQ + (w * 16 + fr) * 128 + ks * 32 + fq);

  const f32x4 zz = {0.f, 0.f, 0.f, 0.f};
  f32x4 sA[32];  // scores [16 q][512 keys] in C-layout, 128 VGPRs
#pragma unroll
  for (int i = 0; i < 32; ++i) sA[i] = zz;

#pragma unroll
  for (int kt = 0; kt < 8; ++kt) {
    __syncthreads();
    {  // stage kh tile [64 keys][128 dk]
      const int lrow = lane >> 4, lc = (lane & 15) * 8;
#pragma unroll
      for (int i = 0; i < 4; ++i) {
        const int rbase = w * 16 + i * 4;
        gl_lds16(KH + ((size_t)(bnh * 512 + kt * 64 + rbase + lrow)) * 128 + lc,
                 (void*)(lKV + rbase * 128));
      }
    }
    __syncthreads();
#pragma unroll
    for (int ks = 0; ks < 4; ++ks)
#pragma unroll
      for (int n = 0; n < 4; ++n) {
        short8 bf = *(const short8*)(lKV + (n * 16 + fr) * 128 + ks * 32 + fq);
        sA[kt * 4 + n] = __builtin_amdgcn_mfma_f32_16x16x32_bf16(af[ks], bf, sA[kt * 4 + n], 0, 0, 0);
      }
  }

  // two-pass softmax (scale already folded into qh); row = quad*4+r, col = ct*16+fr
  float linv[4];
#pragma unroll
  for (int r = 0; r < 4; ++r) {
    float mr = -3.0e38f;
#pragma unroll
    for (int ct = 0; ct < 32; ++ct) {
      float vv = sA[ct][r];
      vv = (lM[ct * 16 + fr] != 0.0f) ? -10000.0f : vv;
      sA[ct][r] = vv;
      mr = fmaxf(mr, vv);
    }
    mr = fmaxf(mr, __shfl_xor(mr, 1, 64));
    mr = fmaxf(mr, __shfl_xor(mr, 2, 64));
    mr = fmaxf(mr, __shfl_xor(mr, 4, 64));
    mr = fmaxf(mr, __shfl_xor(mr, 8, 64));
    float lr = 0.f;
#pragma unroll
    for (int ct = 0; ct < 32; ++ct) {
      float p = __expf(sA[ct][r] - mr);   // masked -> exp(-1e4 - mr) = 0.0f
      sA[ct][r] = p;
      lr += p;
    }
    lr += __shfl_xor(lr, 1, 64);
    lr += __shfl_xor(lr, 2, 64);
    lr += __shfl_xor(lr, 4, 64);
    lr += __shfl_xor(lr, 8, 64);
    linv[r] = 1.0f / lr;
  }

  // PV: stream vh^T chunks; P goes C-layout -> LDS -> A-operand layout
  f32x4 zA[8];
#pragma unroll
  for (int n = 0; n < 8; ++n) zA[n] = zz;
  u16* myP = lP[w];

#pragma unroll
  for (int kt = 0; kt < 8; ++kt) {
    __syncthreads();
    {  // stage vh^T chunk [128 dk][64 keys]
      const int lrow = lane >> 3, lc = (lane & 7) * 8;
#pragma unroll
      for (int i = 0; i < 4; ++i) {
        const int rbase = w * 32 + i * 8;
        gl_lds16(VT + ((size_t)(bnh * 128 + rbase + lrow)) * 512 + kt * 64 + lc,
                 (void*)(lKV + rbase * 64));
      }
    }
    __syncthreads();
#pragma unroll
    for (int n = 0; n < 4; ++n)
#pragma unroll
      for (int r = 0; r < 4; ++r)
        myP[(quad * 4 + r) * 72 + n * 16 + fr] = f2bf(sA[kt * 4 + n][r]);
#pragma unroll
    for (int ks = 0; ks < 2; ++ks) {
      short8 ap = *(const short8*)(myP + fr * 72 + ks * 32 + fq);
#pragma unroll
      for (int n = 0; n < 8; ++n) {
        short8 bv = *(const short8*)(lKV + (n * 16 + fr) * 64 + ks * 32 + fq);
        zA[n] = __builtin_amdgcn_mfma_f32_16x16x32_bf16(ap, bv, zA[n], 0, 0, 0);
      }
    }
  }

  // epilogue: z / l -> Z2[b*512+s][head*125+dk] bf16
#pragma unroll
  for (int n = 0; n < 8; ++n)
#pragma unroll
    for (int r = 0; r < 4; ++r) {
      const int dk = n * 16 + fr;
      if (dk < 125) {
        const int sg = qt * 64 + w * 16 + quad * 4 + r;
        const float val = zA[n][r] * linv[r];
        Z2[((size_t)(b * 512 + sg)) * 1024 + head * 125 + dk] = f2bf(val);
      }
    }
}

// ---------------- LayerNorm over H=1000, 1 block per row --------------------
__global__ __launch_bounds__(256) void ln_kernel(
    const float* __restrict__ Y, const float* __restrict__ g,
    const float* __restrict__ be, float* __restrict__ out) {
  const size_t row = blockIdx.x;
  const int t = threadIdx.x;
  const float* yr = Y + row * 1000;
  float4 x = make_float4(0.f, 0.f, 0.f, 0.f);
  if (t < 250) x = *(const float4*)(yr + t * 4);
  float s1 = x.x + x.y + x.z + x.w;
  float s2 = x.x * x.x + x.y * x.y + x.z * x.z + x.w * x.w;
#pragma unroll
  for (int off = 1; off < 64; off <<= 1) {
    s1 += __shfl_xor(s1, off, 64);
    s2 += __shfl_xor(s2, off, 64);
  }
  __shared__ float r1[4], r2[4];
  const int w = t >> 6, lane = t & 63;
  if (lane == 0) { r1[w] = s1; r2[w] = s2; }
  __syncthreads();
  const float S1 = r1[0] + r1[1] + r1[2] + r1[3];
  const float S2 = r2[0] + r2[1] + r2[2] + r2[3];
  const float mu = S1 * 0.001f;
  const float var = S2 * 0.001f - mu * mu;
  const float rstd = rsqrtf(var + 1e-5f);
  if (t < 250) {
    float4 gg = *(const float4*)(g + t * 4);
    float4 bb = *(const float4*)(be + t * 4);
    float4 o;
    o.x = (x.x - mu) * rstd * gg.x + bb.x;
    o.y = (x.y - mu) * rstd * gg.y + bb.y;
    o.z = (x.z - mu) * rstd * gg.z + bb.z;
    o.w = (x.w - mu) * rstd * gg.w + bb.w;
    *(float4*)(out + row * 1000 + t * 4) = o;
  }
}

// ---------------------------------------------------------------------------
extern "C" void kernel_launch(void* const* d_in, const int* in_sizes, int n_in,
                              void* d_out, int out_size, void* d_ws, size_t ws_size,
                              hipStream_t stream) {
  const float* q   = (const float*)d_in[0];
  const float* k   = (const float*)d_in[1];
  const float* v   = (const float*)d_in[2];
  const int*   mk  = (const int*)  d_in[3];
  const float* wqw = (const float*)d_in[4];
  const float* wqb = (const float*)d_in[5];
  const float* wkw = (const float*)d_in[6];
  const float* wkb = (const float*)d_in[7];
  const float* wvw = (const float*)d_in[8];
  const float* wvb = (const float*)d_in[9];
  const float* wow = (const float*)d_in[10];
  const float* wob = (const float*)d_in[11];
  const float* lng = (const float*)d_in[12];
  const float* lnb = (const float*)d_in[13];
  u16* ws16 = (u16*)d_ws;

  cvt_kernel<<<dim3(200704), dim3(128), 0, stream>>>(q, k, v, wqw, wkw, wvw, wow, ws16);
  zpad_kernel<<<dim3(2048), dim3(256), 0, stream>>>(ws16);
  gemm_bt<<<dim3(1024, 1, 3), dim3(512), 0, stream>>>(ws16, wqb, wkb, wvb, wob, q, 0);
  attn_kernel<<<dim3(8, 1024), dim3(256), 0, stream>>>(ws16, mk);
  gemm_bt<<<dim3(1024, 1, 1), dim3(512), 0, stream>>>(ws16, wqb, wkb, wvb, wob, q, 3);
  ln_kernel<<<dim3(65536), dim3(256), 0, stream>>>(
      (const float*)((const char*)d_ws + Y_BYTE), lng, lnb, (float*)d_out);
}